// Round 9
// baseline (134.032 us; speedup 1.0000x reference)
//
#include <hip/hip_runtime.h>
#include <math.h>

// DirectionalContrastiveLoss — N=8, C=192, H=W=112, T=0.1
//
// R9: 14 independent waves/CU.
//  - tile 2 rows x 56 cols (wide 58-float rows: FETCH=80MB proven in R6).
//  - NT=256 = 4 waves; wave w owns channels [w*48, w*48+48) with its OWN
//    double-buffered LDS tile (KCH=2 -> one float2 group) -> ZERO barriers in
//    the 24-chunk hot loop; waves drift freely. 896 blocks x 4 = 14 waves/CU
//    (3.5/SIMD) hide VMEM latency (R8's 1-wave blocks = 3.5 waves/CU, 75%
//    stalled; R5-R8 trajectory shows waves/CU is the controlling variable).
//  - 2 x-adjacent px/lane, 3x4 window as 6 ds_read_b128 (proven in R8).
//  - epilogue: ssq merge -> inv-norm plane (barrier), dot merge via padded
//    LDS exchange (stride 19), loss on lanes 0..13 of every wave (barrier),
//    one double partial per block into d_ws.

namespace {
constexpr int N_ = 8, C_ = 192, H_ = 112, W_ = 112;
constexpr int HW = H_ * W_;
constexpr int TH = 2;                  // px rows per block
constexpr int WSX = 56;                // px cols per block
constexpr int RS = 58;                 // slot row stride (floats/float2 slots)
constexpr int TILE_E = 4 * RS;         // 232 slots (4 halo rows)
constexpr int NT = 256;                // 4 waves
constexpr int NWV = 4;
constexpr int CW = C_ / NWV;           // 48 channels per wave
constexpr int KCH = 2;                 // channels per chunk = 1 float2 group
constexpr int NCHUNK = CW / KCH;       // 24
constexpr int NS4 = TILE_E - 3 * 64;   // 40 lanes own a 4th slot
constexpr int NPAIR = 56;              // px-pairs per tile
constexpr int EXS = 19;                // exchange stride (odd -> no conflicts)
constexpr int GX = W_ / WSX, GY = H_ / TH;   // 2, 56
constexpr int NBLK = GX * GY * N_;     // 896
constexpr float INV_T = 10.0f;
constexpr double TOTAL = (double)N_ * N_ * H_ * W_;  // 802816
}

__device__ __forceinline__ float sel3(int d, float a, float b, float c) {
    float r = (d < 0) ? a : b;
    return (d > 0) ? c : r;
}

__device__ __forceinline__ float px_loss(
    const float l[3][3], int gi, int gj, int n,
    const int* __restrict__ labels, const int* __restrict__ dirs)
{
    const int pix = gi * W_ + gj;
    float denom = 0.f, sumlog = 0.f;
#pragma unroll
    for (int m = 0; m < N_; ++m) {
        int d0 = dirs[((m * 2 + 0) * H_ + gi) * W_ + gj];
        int d1 = dirs[((m * 2 + 1) * H_ + gi) * W_ + gj];
        float r0 = sel3(d1, l[0][0], l[0][1], l[0][2]);
        float r1 = sel3(d1, l[1][0], l[1][1], l[1][2]);
        float r2 = sel3(d1, l[2][0], l[2][1], l[2][2]);
        float lm = sel3(d0, r0, r1, r2);
        int labm = labels[m * HW + pix];
        int labn = labels[n * HW + (gi + d0) * W_ + (gj + d1)];
        bool msk = (labm == labn);
        float e = msk ? __expf(lm) : 0.f;
        denom += e;
        sumlog += msk ? lm : -INFINITY;
    }
    return 8.0f * __logf(denom + 1e-6f) - sumlog;
}

extern "C" __global__ void __launch_bounds__(NT, 4)
dcl_main(const float* __restrict__ feat,
         const int* __restrict__ labels,
         const int* __restrict__ dirs,
         double* __restrict__ partial, int use_partial)
{
    alignas(16) __shared__ float2 tl[NWV * 2 * TILE_E];   // 14848 B
    __shared__ float ex[NWV * NPAIR * EXS];               // 17024 B
    __shared__ float ssq[NWV * TILE_E];                   // 3712 B
    __shared__ float ssb[TILE_E];                         // 928 B
    __shared__ float red[NWV];

    const int tid  = threadIdx.x;
    const int lane = tid & 63;
    const int wv   = tid >> 6;
    const int gx0 = blockIdx.x * WSX;
    const int gy0 = blockIdx.y * TH;
    const int n   = blockIdx.z;

    // ---- owned staging slots -> clamped global offsets
    const bool has4 = (lane < NS4);
    int gofs[4];
    #pragma unroll
    for (int sI = 0; sI < 4; ++sI) {
        int s = lane + sI * 64;
        if (s >= TILE_E) s = TILE_E - 1;
        int r = s / RS, c = s - r * RS;
        gofs[sI] = min(max(gy0 + r - 1, 0), H_ - 1) * W_
                 + min(max(gx0 + c - 1, 0), W_ - 1);
    }

    const bool is_px = (lane < NPAIR);
    const int py  = lane / (WSX / 2);          // 0..1 (for is_px lanes)
    const int pxp = lane - py * (WSX / 2);     // 0..27
    const int wb  = py * RS + 2 * pxp;         // float2 idx, 16B aligned

    const float* __restrict__ wplane =
        feat + ((size_t)n * C_ + (size_t)wv * CW) * HW;
    float2* __restrict__ mytl = tl + wv * 2 * TILE_E;

    float sA[9], sB[9];
    #pragma unroll
    for (int k = 0; k < 9; ++k) { sA[k] = 0.f; sB[k] = 0.f; }
    float ss[4] = {0.f, 0.f, 0.f, 0.f};

    // ---- prologue: chunk 0 -> buffer 0 (wave-private, no barrier ever)
    {
        float a[4], b[4];
        #pragma unroll
        for (int i = 0; i < 3; ++i) { a[i] = wplane[gofs[i]]; b[i] = wplane[HW + gofs[i]]; }
        if (has4) { a[3] = wplane[gofs[3]]; b[3] = wplane[HW + gofs[3]]; }
        #pragma unroll
        for (int i = 0; i < 3; ++i) {
            mytl[lane + i * 64] = make_float2(a[i], b[i]);
            ss[i] = fmaf(a[i], a[i], fmaf(b[i], b[i], ss[i]));
        }
        if (has4) {
            mytl[lane + 192] = make_float2(a[3], b[3]);
            ss[3] = fmaf(a[3], a[3], fmaf(b[3], b[3], ss[3]));
        }
    }

    // ---- hot loop: 24 chunks, wave-private double buffer, ZERO barriers
    for (int t = 0; t < NCHUNK; ++t) {
        float a[4], b[4];
        const bool more = (t + 1 < NCHUNK);
        if (more) {
            const float* __restrict__ p = wplane + (size_t)(t + 1) * KCH * HW;
            #pragma unroll
            for (int i = 0; i < 3; ++i) { a[i] = p[gofs[i]]; b[i] = p[HW + gofs[i]]; }
            if (has4) { a[3] = p[gofs[3]]; b[3] = p[HW + gofs[3]]; }
        }

        if (is_px) {
            const float2* __restrict__ cp = mytl + (t & 1) * TILE_E;
            float4 L0 = *reinterpret_cast<const float4*>(cp + wb);
            float4 R0 = *reinterpret_cast<const float4*>(cp + wb + 2);
            float4 L1 = *reinterpret_cast<const float4*>(cp + wb + RS);
            float4 R1 = *reinterpret_cast<const float4*>(cp + wb + RS + 2);
            float4 L2 = *reinterpret_cast<const float4*>(cp + wb + 2 * RS);
            float4 R2 = *reinterpret_cast<const float4*>(cp + wb + 2 * RS + 2);
            const float fAx = L1.z, fAy = L1.w;     // px A = (row1, col 2pxp+1)
            const float fBx = R1.x, fBy = R1.y;     // px B = (row1, col 2pxp+2)
            sA[0] = fmaf(fAx, L0.x, fmaf(fAy, L0.y, sA[0]));
            sA[1] = fmaf(fAx, L0.z, fmaf(fAy, L0.w, sA[1]));
            sA[2] = fmaf(fAx, R0.x, fmaf(fAy, R0.y, sA[2]));
            sA[3] = fmaf(fAx, L1.x, fmaf(fAy, L1.y, sA[3]));
            sA[4] = fmaf(fAx, L1.z, fmaf(fAy, L1.w, sA[4]));
            sA[5] = fmaf(fAx, R1.x, fmaf(fAy, R1.y, sA[5]));
            sA[6] = fmaf(fAx, L2.x, fmaf(fAy, L2.y, sA[6]));
            sA[7] = fmaf(fAx, L2.z, fmaf(fAy, L2.w, sA[7]));
            sA[8] = fmaf(fAx, R2.x, fmaf(fAy, R2.y, sA[8]));
            sB[0] = fmaf(fBx, L0.z, fmaf(fBy, L0.w, sB[0]));
            sB[1] = fmaf(fBx, R0.x, fmaf(fBy, R0.y, sB[1]));
            sB[2] = fmaf(fBx, R0.z, fmaf(fBy, R0.w, sB[2]));
            sB[3] = fmaf(fBx, L1.z, fmaf(fBy, L1.w, sB[3]));
            sB[4] = fmaf(fBx, R1.x, fmaf(fBy, R1.y, sB[4]));
            sB[5] = fmaf(fBx, R1.z, fmaf(fBy, R1.w, sB[5]));
            sB[6] = fmaf(fBx, L2.z, fmaf(fBy, L2.w, sB[6]));
            sB[7] = fmaf(fBx, R2.x, fmaf(fBy, R2.y, sB[7]));
            sB[8] = fmaf(fBx, R2.z, fmaf(fBy, R2.w, sB[8]));
        }

        if (more) {
            float2* __restrict__ np = mytl + ((t + 1) & 1) * TILE_E;
            #pragma unroll
            for (int i = 0; i < 3; ++i) {
                np[lane + i * 64] = make_float2(a[i], b[i]);
                ss[i] = fmaf(a[i], a[i], fmaf(b[i], b[i], ss[i]));
            }
            if (has4) {
                np[lane + 192] = make_float2(a[3], b[3]);
                ss[3] = fmaf(a[3], a[3], fmaf(b[3], b[3], ss[3]));
            }
        }
    }

    // ---- publish per-wave partials
    ssq[wv * TILE_E + lane]       = ss[0];
    ssq[wv * TILE_E + lane + 64]  = ss[1];
    ssq[wv * TILE_E + lane + 128] = ss[2];
    if (has4) ssq[wv * TILE_E + lane + 192] = ss[3];
    if (is_px) {
        float* e = ex + (wv * NPAIR + lane) * EXS;
        #pragma unroll
        for (int k = 0; k < 9; ++k) { e[k] = sA[k]; e[9 + k] = sB[k]; }
    }
    __syncthreads();

    // ---- inv-norm plane (232 threads)
    if (tid < TILE_E) {
        float t = ssq[tid] + ssq[TILE_E + tid]
                + ssq[2 * TILE_E + tid] + ssq[3 * TILE_E + tid];
        ssb[tid] = 1.0f / fmaxf(sqrtf(t), 1e-12f);
    }
    __syncthreads();

    // ---- loss: lanes 0..13 of each wave handle pair = wv*14 + lane
    float lp = 0.0f;
    if (lane < NPAIR / NWV) {
        const int pr  = wv * (NPAIR / NWV) + lane;
        const int ppy = pr / (WSX / 2);
        const int ppx = pr - ppy * (WSX / 2);
        const int wbs = ppy * RS + 2 * ppx;    // float idx into ssb

        float sa[9], sb[9];
        #pragma unroll
        for (int k = 0; k < 9; ++k) { sa[k] = 0.f; sb[k] = 0.f; }
        #pragma unroll
        for (int w = 0; w < NWV; ++w) {
            const float* e = ex + (w * NPAIR + pr) * EXS;
            #pragma unroll
            for (int k = 0; k < 9; ++k) { sa[k] += e[k]; sb[k] += e[9 + k]; }
        }
        float iv[3][4];
        #pragma unroll
        for (int r = 0; r < 3; ++r)
            #pragma unroll
            for (int c = 0; c < 4; ++c)
                iv[r][c] = ssb[wbs + r * RS + c];
        const float iA = iv[1][1] * INV_T, iB = iv[1][2] * INV_T;
        float lA[3][3], lB[3][3];
        #pragma unroll
        for (int r = 0; r < 3; ++r)
            #pragma unroll
            for (int c = 0; c < 3; ++c) {
                lA[r][c] = sa[r * 3 + c] * iA * iv[r][c];
                lB[r][c] = sb[r * 3 + c] * iB * iv[r][c + 1];
            }
        const int gi = gy0 + ppy, gj = gx0 + 2 * ppx;
        lp = px_loss(lA, gi, gj, n, labels, dirs)
           + px_loss(lB, gi, gj + 1, n, labels, dirs);
    }
    #pragma unroll
    for (int off = 32; off > 0; off >>= 1) lp += __shfl_down(lp, off, 64);
    if (lane == 0) red[wv] = lp;
    __syncthreads();
    if (tid == 0) {
        const int bid = (blockIdx.z * gridDim.y + blockIdx.y) * gridDim.x + blockIdx.x;
        float t = red[0] + red[1] + red[2] + red[3];
        if (use_partial) partial[bid] = (double)t;
        else atomicAdd(partial, (double)t);
    }
}

extern "C" __global__ void __launch_bounds__(256)
dcl_final(const double* __restrict__ partial, float* __restrict__ out, int nblk)
{
    const int tid = threadIdx.x;
    double s = 0.0;
    for (int i = tid; i < nblk; i += 256) s += partial[i];
    #pragma unroll
    for (int off = 32; off > 0; off >>= 1) s += __shfl_down(s, off, 64);
    __shared__ double red[4];
    const int lane = tid & 63, wv = tid >> 6;
    if (lane == 0) red[wv] = s;
    __syncthreads();
    if (tid == 0) out[0] = (float)((red[0] + red[1] + red[2] + red[3]) / TOTAL);
}

extern "C" void kernel_launch(void* const* d_in, const int* in_sizes, int n_in,
                              void* d_out, int out_size, void* d_ws, size_t ws_size,
                              hipStream_t stream) {
    const float* feat   = (const float*)d_in[0];
    const int*   labels = (const int*)d_in[1];
    const int*   dirs   = (const int*)d_in[2];
    double* acc = (double*)d_ws;
    float*  out = (float*)d_out;

    const int use_partial = (ws_size >= (size_t)NBLK * sizeof(double)) ? 1 : 0;
    if (!use_partial) hipMemsetAsync(acc, 0, sizeof(double), stream);
    dim3 grid(GX, GY, N_);                // (2, 56, 8) = 896 blocks
    dcl_main<<<grid, NT, 0, stream>>>(feat, labels, dirs, acc, use_partial);
    dcl_final<<<1, 256, 0, stream>>>(acc, out, use_partial ? NBLK : 1);
}